// Round 1
// baseline (294.857 us; speedup 1.0000x reference)
//
#include <hip/hip_runtime.h>

// CBOW negative-sampling loss on MI355X.
// B=131072 elems, D=128, 16 rows (1 ctx + 15 neg) per elem, all of form
// log_sigmoid(-dot(row, emb_input)).  Output: -mean over B.
//
// Layout: 8 lanes per batch element (group), 8 elements per wave.
// Lane `sub` holds floats {sub*4+0..3} of float4-chunks {sub+8k, k=0..3}
// -> every row-load instruction is 8 groups x 128B contiguous = 1KB/wave.
// Dot reduce = 3 shfl_xor steps shared across 8 elements.

#define B_TOT 131072
#define DDIM  128
#define NNEG  15
#define NROWS 16
#define BPB   32          // batch elems per block (4 waves x 8)
#define NBLK  (B_TOT / BPB)   // 4096

__device__ __forceinline__ float log_sigmoid(float x) {
    // stable: min(x,0) - log1p(exp(-|x|))
    return fminf(x, 0.0f) - log1pf(__expf(-fabsf(x)));
}

__global__ __launch_bounds__(256, 4) void cbow_main(
    const int* __restrict__ target, const int* __restrict__ context,
    const int* __restrict__ neg_idx, const float* __restrict__ dmask,
    const float* __restrict__ Wt, const float* __restrict__ Wc,
    float* __restrict__ block_sums)
{
    const int tid  = threadIdx.x;
    const int wave = tid >> 6;
    const int lane = tid & 63;
    const int grp  = lane >> 3;   // 0..7  which batch elem in wave
    const int sub  = lane & 7;    // 0..7  slice of D
    const int b = blockIdx.x * BPB + wave * 8 + grp;

    // emb_input = W_target[target[b]] * dropout_mask[b]   (16 floats/lane)
    const int tgt = target[b];
    const float4* trow = (const float4*)(Wt + (size_t)tgt * DDIM);
    const float4* mrow = (const float4*)(dmask + (size_t)b * DDIM);
    float4 e[4];
#pragma unroll
    for (int k = 0; k < 4; ++k) {
        float4 w = trow[sub + 8 * k];
        float4 m = mrow[sub + 8 * k];
        e[k] = make_float4(w.x * m.x, w.y * m.y, w.z * m.z, w.w * m.w);
    }

    // 16 row indices: context + 15 negatives (all same functional form)
    int ridx[NROWS];
    ridx[0] = context[b];
#pragma unroll
    for (int n = 0; n < NNEG; ++n)
        ridx[n + 1] = neg_idx[(size_t)b * NNEG + n];

    float acc = 0.0f;
#pragma unroll 2
    for (int r = 0; r < NROWS; ++r) {
        const float4* crow = (const float4*)(Wc + (size_t)ridx[r] * DDIM);
        float p = 0.0f;
#pragma unroll
        for (int k = 0; k < 4; ++k) {
            float4 c = crow[sub + 8 * k];
            p += c.x * e[k].x + c.y * e[k].y + c.z * e[k].z + c.w * e[k].w;
        }
        // reduce dot across the 8 lanes of this group
        p += __shfl_xor(p, 1);
        p += __shfl_xor(p, 2);
        p += __shfl_xor(p, 4);
        acc += log_sigmoid(-p);
    }
    // keep one copy per group, then sum the 8 groups across the wave
    if (sub != 0) acc = 0.0f;
    acc += __shfl_xor(acc, 8);
    acc += __shfl_xor(acc, 16);
    acc += __shfl_xor(acc, 32);

    __shared__ float wsum[4];
    if (lane == 0) wsum[wave] = acc;
    __syncthreads();
    if (tid == 0)
        block_sums[blockIdx.x] = wsum[0] + wsum[1] + wsum[2] + wsum[3];
}

__global__ __launch_bounds__(256) void cbow_final(
    const float* __restrict__ block_sums, float* __restrict__ out)
{
    float s = 0.0f;
    for (int i = threadIdx.x; i < NBLK; i += 256) s += block_sums[i];
#pragma unroll
    for (int m = 1; m < 64; m <<= 1) s += __shfl_xor(s, m);
    __shared__ float ws[4];
    if ((threadIdx.x & 63) == 0) ws[threadIdx.x >> 6] = s;
    __syncthreads();
    if (threadIdx.x == 0)
        out[0] = -(ws[0] + ws[1] + ws[2] + ws[3]) / (float)B_TOT;
}

extern "C" void kernel_launch(void* const* d_in, const int* in_sizes, int n_in,
                              void* d_out, int out_size, void* d_ws, size_t ws_size,
                              hipStream_t stream) {
    const int*   target  = (const int*)d_in[0];
    const int*   context = (const int*)d_in[1];
    const int*   neg_idx = (const int*)d_in[2];
    const float* dmask   = (const float*)d_in[3];
    const float* Wt      = (const float*)d_in[4];
    const float* Wc      = (const float*)d_in[5];
    float* out = (float*)d_out;
    float* block_sums = (float*)d_ws;   // 4096 floats = 16 KB

    cbow_main<<<NBLK, 256, 0, stream>>>(target, context, neg_idx, dmask, Wt, Wc,
                                        block_sums);
    cbow_final<<<1, 256, 0, stream>>>(block_sums, out);
}